// Round 1
// baseline (3198.198 us; speedup 1.0000x reference)
//
#include <hip/hip_runtime.h>
#include <hip/hip_bf16.h>

#define B_N 1024
#define H_N 256
#define O_N 128
#define D_N 64

// d_out offsets (f32 elements), reference tuple order
#define OFF_NEWH      0
#define OFF_NEWDELTA  262144
#define OFF_NEWINST   524288
#define OFF_NEWPJ     786432
#define OFF_NEWMEAN   67895296
#define OFF_NEWT      68157440
#define OFF_OUT       68158464
#define OFF_HCOPY     68289536
#define OFF_DELTAOUT  68551680
#define OFF_HNORM     68682752
#define OFF_DNORM     68683776
#define OFF_PJNORM    68684800
#define OFF_JAC       68685824

typedef __attribute__((ext_vector_type(8))) short short8;
typedef __attribute__((ext_vector_type(4))) float f32x4;

__device__ __forceinline__ short f2bf(float f){
  union { float f; unsigned u; } v; v.f = f;
  unsigned r = v.u + 0x7fffu + ((v.u >> 16) & 1u);
  return (short)(r >> 16);
}

__device__ __forceinline__ float wave_reduce_sum(float v){
  #pragma unroll
  for (int off = 32; off > 0; off >>= 1) v += __shfl_xor(v, off);
  return v;
}

// ---------------------------------------------------------------------------
// Kernel 1: GRU gates, new_h, a-vectors, h copy, new_t, h_norm
// ---------------------------------------------------------------------------
__global__ __launch_bounds__(256) void gates_kernel(
    const float* __restrict__ x, const float* __restrict__ h, const float* __restrict__ tt,
    const float* __restrict__ Wiz, const float* __restrict__ biz, const float* __restrict__ Whz,
    const float* __restrict__ Wir, const float* __restrict__ bir, const float* __restrict__ Whr,
    const float* __restrict__ Win, const float* __restrict__ bin_, const float* __restrict__ Whn,
    const float* __restrict__ bhn,
    float* __restrict__ dout, float* __restrict__ ws)
{
  int b = blockIdx.x, j = threadIdx.x;
  __shared__ float xs[64];
  __shared__ float hs[256];
  __shared__ float red[4];
  if (j < 64) xs[j] = x[b*64 + j];
  float hj = h[b*256 + j];
  hs[j] = hj;
  __syncthreads();

  float zp = biz[j], rp = bir[j], np = bin_[j], g = bhn[j];
  #pragma unroll 8
  for (int k = 0; k < 64; k++){
    float xv = xs[k];
    zp = fmaf(xv, Wiz[k*256 + j], zp);
    rp = fmaf(xv, Wir[k*256 + j], rp);
    np = fmaf(xv, Win[k*256 + j], np);
  }
  #pragma unroll 8
  for (int k = 0; k < 256; k++){
    float hv = hs[k];
    zp = fmaf(hv, Whz[k*256 + j], zp);
    rp = fmaf(hv, Whr[k*256 + j], rp);
    g  = fmaf(hv, Whn[k*256 + j], g);
  }
  float r = 1.f / (1.f + expf(-rp));
  float z = 1.f / (1.f + expf(-zp));
  float n = tanhf(np + r*g);
  float nh = (1.f - z)*n + z*hj;

  float dz = z*(1.f - z);
  float dn = 1.f - n*n;
  float drv = r*(1.f - r);
  float az = (hj - n)*dz;
  float an = (1.f - z)*dn*r;
  float ar = (1.f - z)*dn*g*drv;

  dout[OFF_NEWH   + b*256 + j] = nh;
  dout[OFF_NEWMEAN+ b*256 + j] = nh;
  dout[OFF_HCOPY  + b*256 + j] = hj;
  ws[0*262144 + b*256 + j] = z;
  ws[1*262144 + b*256 + j] = az;
  ws[2*262144 + b*256 + j] = an;
  ws[3*262144 + b*256 + j] = ar;

  float s = wave_reduce_sum(nh*nh);
  if ((j & 63) == 0) red[j >> 6] = s;
  __syncthreads();
  if (j == 0){
    dout[OFF_HNORM + b] = sqrtf(red[0] + red[1] + red[2] + red[3]);
    dout[OFF_NEWT + b] = tt[b] + 1.f;
  }
}

// ---------------------------------------------------------------------------
// Kernel 2: build jac (written to d_out) + register-resident implicit-pivot
// Gauss-Jordan solve of jac * x = delta - inst_delta.  One block per batch.
// Thread t owns column (t&255), rows [64*(t>>8), +64) in registers.
// ---------------------------------------------------------------------------
__global__ __launch_bounds__(1024) void solve_kernel(
    const float* __restrict__ Whz, const float* __restrict__ Whn, const float* __restrict__ Whr,
    const float* __restrict__ ws, const float* __restrict__ delta,
    const float* __restrict__ inst_delta, float* __restrict__ dout)
{
  int b = blockIdx.x, tid = threadIdx.x;
  int cc = tid & 255, rb = tid >> 8;

  __shared__ float colbuf[2][256];
  __shared__ float rowbuf[256];
  __shared__ float rhs[256];
  __shared__ float pivval[256];
  __shared__ int   perm[256];
  __shared__ float usedf[256];
  __shared__ float s_ipv;
  __shared__ int   s_p;

  float a_z = ws[1*262144 + b*256 + cc];
  float a_n = ws[2*262144 + b*256 + cc];
  float a_r = ws[3*262144 + b*256 + cc];
  float zc  = ws[0*262144 + b*256 + cc];

  float A[64];
  float* jac_out = dout + OFF_JAC + (size_t)b*65536;
  {
    const int rbase = rb*64;
    #pragma unroll
    for (int i = 0; i < 64; i++){
      int r = rbase + i;
      int idx = r*256 + cc;
      float v = fmaf(Whz[idx], a_z, fmaf(Whn[idx], a_n, Whr[idx]*a_r));
      if (r == cc) v += zc;
      A[i] = v;
      jac_out[idx] = v;
    }
  }
  if (tid < 256){
    rhs[tid] = delta[b*256 + tid] - inst_delta[b*256 + tid];
    usedf[tid] = 0.f;
  }
  if (cc == 0){
    #pragma unroll
    for (int i = 0; i < 64; i++) colbuf[0][rb*64 + i] = A[i];
  }
  __syncthreads();

  for (int k = 0; k < 256; k++){
    const int kb = k & 1;
    // --- pivot selection (wave 0) ---
    if (tid < 64){
      float best = -1.f; int bidx = 0;
      #pragma unroll
      for (int q = 0; q < 4; q++){
        int rr = tid*4 + q;
        float sc = (usedf[rr] != 0.f) ? -1.f : fabsf(colbuf[kb][rr]);
        if (sc > best){ best = sc; bidx = rr; }
      }
      #pragma unroll
      for (int off = 32; off > 0; off >>= 1){
        float ob = __shfl_xor(best, off);
        int   oi = __shfl_xor(bidx, off);
        if (ob > best || (ob == best && oi < bidx)){ best = ob; bidx = oi; }
      }
      if (tid == 0){
        float pv = colbuf[kb][bidx];
        s_p = bidx;
        s_ipv = 1.f / pv;
        pivval[k] = pv;
        perm[k] = bidx;
        usedf[bidx] = 1.f;
        colbuf[kb][bidx] = 0.f;   // forces m_p = 0 everywhere below
      }
    }
    __syncthreads();
    const int p = s_p;
    const float ipv = s_ipv;
    // --- extract pivot row to rowbuf; update rhs ---
    if (rb == (p >> 6)){
      const int pl = p & 63;
      float sel = 0.f;
      #pragma unroll
      for (int i = 0; i < 64; i++) sel = (i == pl) ? A[i] : sel;
      rowbuf[cc] = sel;
    }
    if (tid < 256 && tid != p){
      rhs[tid] -= (colbuf[kb][tid] * ipv) * rhs[p];
    }
    __syncthreads();
    // --- rank-1 elimination update ---
    {
      const float sfac = rowbuf[cc] * ipv;
      const float* cb = &colbuf[kb][rb*64];
      #pragma unroll
      for (int i = 0; i < 64; i++) A[i] = fmaf(-cb[i], sfac, A[i]);
      if (k < 255 && cc == (k + 1)){
        #pragma unroll
        for (int i = 0; i < 64; i++) colbuf[kb ^ 1][rb*64 + i] = A[i];
      }
    }
    __syncthreads();
  }

  if (tid < 256){
    float xv = rhs[perm[tid]] / pivval[tid];
    dout[OFF_NEWDELTA + b*256 + tid] = xv;
    colbuf[0][tid] = xv*xv;
  }
  __syncthreads();
  if (tid < 64){
    float s = colbuf[0][tid] + colbuf[0][tid+64] + colbuf[0][tid+128] + colbuf[0][tid+192];
    s = wave_reduce_sum(s);
    if (tid == 0) dout[OFF_DNORM + b] = sqrtf(s);
  }
}

// ---------------------------------------------------------------------------
// Kernel 3: new_prod_jac[b] = prod_jac[b] @ jac[b]  (bf16 MFMA, f32 LDS pad-33)
// one block (512 thr, 8 waves as 2x4) per batch; + Frobenius norm epilogue
// ---------------------------------------------------------------------------
__global__ __launch_bounds__(512) void pj_gemm_kernel(
    const float* __restrict__ prod_jac, const float* __restrict__ jac,
    float* __restrict__ out_pj, float* __restrict__ out_norm)
{
  int b = blockIdx.x, tid = threadIdx.x;
  int l = tid & 63, wid = tid >> 6;
  int wm = wid >> 2, wn = wid & 3;
  int lr = l & 15, lg = l >> 4;

  __shared__ float As[256*33];
  __shared__ float Bs[256*33];

  const float* Ag = prod_jac + (size_t)b*65536;
  const float* Bg = jac      + (size_t)b*65536;

  f32x4 acc[8][4];
  #pragma unroll
  for (int i = 0; i < 8; i++)
    #pragma unroll
    for (int jn = 0; jn < 4; jn++) acc[i][jn] = (f32x4){0.f,0.f,0.f,0.f};

  const int arow = tid >> 1, acolb = (tid & 1)*16;
  const int bk = tid >> 4, bcolb = (tid & 15)*16;

  for (int kt = 0; kt < 8; ++kt){
    const int k0 = kt*32;
    __syncthreads();
    {
      const float4* asrc = (const float4*)(Ag + arow*256 + k0 + acolb);
      float* ad = &As[arow*33 + acolb];
      #pragma unroll
      for (int q = 0; q < 4; q++){
        float4 v = asrc[q];
        ad[q*4+0]=v.x; ad[q*4+1]=v.y; ad[q*4+2]=v.z; ad[q*4+3]=v.w;
      }
      const float4* bsrc = (const float4*)(Bg + (k0 + bk)*256 + bcolb);
      #pragma unroll
      for (int q = 0; q < 4; q++){
        float4 v = bsrc[q];
        Bs[(bcolb+q*4+0)*33 + bk] = v.x;
        Bs[(bcolb+q*4+1)*33 + bk] = v.y;
        Bs[(bcolb+q*4+2)*33 + bk] = v.z;
        Bs[(bcolb+q*4+3)*33 + bk] = v.w;
      }
    }
    __syncthreads();

    short8 bfr[4];
    #pragma unroll
    for (int ni = 0; ni < 4; ni++){
      const float* bp = &Bs[(wn*64 + ni*16 + lr)*33 + lg*8];
      short8 t;
      #pragma unroll
      for (int v = 0; v < 8; v++) t[v] = f2bf(bp[v]);
      bfr[ni] = t;
    }
    #pragma unroll
    for (int mi = 0; mi < 8; mi++){
      const float* ap = &As[(wm*128 + mi*16 + lr)*33 + lg*8];
      short8 af;
      #pragma unroll
      for (int v = 0; v < 8; v++) af[v] = f2bf(ap[v]);
      #pragma unroll
      for (int ni = 0; ni < 4; ni++)
        acc[mi][ni] = __builtin_amdgcn_mfma_f32_16x16x32_bf16(af, bfr[ni], acc[mi][ni], 0, 0, 0);
    }
  }

  float nrm = 0.f;
  #pragma unroll
  for (int mi = 0; mi < 8; mi++){
    #pragma unroll
    for (int ni = 0; ni < 4; ni++){
      #pragma unroll
      for (int rr = 0; rr < 4; rr++){
        int row = wm*128 + mi*16 + lg*4 + rr;
        int col = wn*64 + ni*16 + lr;
        float vv = acc[mi][ni][rr];
        out_pj[(size_t)b*65536 + row*256 + col] = vv;
        nrm += vv*vv;
      }
    }
  }
  __syncthreads();
  As[tid] = nrm;
  __syncthreads();
  if (tid < 64){
    float s = 0.f;
    #pragma unroll
    for (int q = 0; q < 8; q++) s += As[tid + q*64];
    s = wave_reduce_sum(s);
    if (tid == 0) out_norm[b] = sqrtf(s);
  }
}

// ---------------------------------------------------------------------------
// Kernel 4: readout (LayerNorm + Wout), out, delta_output, LN-VJP inst_delta
// ---------------------------------------------------------------------------
__global__ __launch_bounds__(256) void readout_kernel(
    const float* __restrict__ y, const float* __restrict__ m,
    const float* __restrict__ ln_scale, const float* __restrict__ ln_bias,
    const float* __restrict__ Wout, const float* __restrict__ bout,
    float* __restrict__ dout)
{
  int b = blockIdx.x, j = threadIdx.x;
  __shared__ float lno[256], xh[256], go[128], red2[256], red[4];

  float hv = dout[OFF_NEWH + b*256 + j];
  float s = wave_reduce_sum(hv);
  if ((j & 63) == 0) red[j >> 6] = s;
  __syncthreads();
  float mu = (red[0] + red[1] + red[2] + red[3]) * (1.f/256.f);
  __syncthreads();
  float d = hv - mu;
  float sv = wave_reduce_sum(d*d);
  if ((j & 63) == 0) red[j >> 6] = sv;
  __syncthreads();
  float var = (red[0] + red[1] + red[2] + red[3]) * (1.f/256.f);
  float rstd = rsqrtf(var + 1e-6f);
  float xhj = d * rstd;
  xh[j] = xhj;
  lno[j] = xhj * ln_scale[j] + ln_bias[j];
  __syncthreads();

  // forward o = lno @ Wout + bout, split across thread halves
  int i = j & 127, half = j >> 7;
  float part = half ? 0.f : bout[i];
  #pragma unroll 8
  for (int jj = half*128; jj < half*128 + 128; jj++)
    part = fmaf(lno[jj], Wout[jj*128 + i], part);
  red2[j] = part;
  __syncthreads();
  if (j < 128){
    float o = red2[j] + red2[j + 128];
    float gv = 2.f * m[b*128 + j] * (o - y[b*128 + j]);
    dout[OFF_OUT + b*128 + j] = o;
    dout[OFF_DELTAOUT + b*128 + j] = gv;
    go[j] = gv;
  }
  __syncthreads();

  // backward through Wout and LayerNorm
  float gl = 0.f;
  const float4* wrow = (const float4*)(Wout + j*128);
  #pragma unroll 8
  for (int q = 0; q < 32; q++){
    float4 w = wrow[q];
    gl = fmaf(w.x, go[q*4+0], gl);
    gl = fmaf(w.y, go[q*4+1], gl);
    gl = fmaf(w.z, go[q*4+2], gl);
    gl = fmaf(w.w, go[q*4+3], gl);
  }
  float gx = gl * ln_scale[j];
  __syncthreads();
  float t1 = wave_reduce_sum(gx);
  if ((j & 63) == 0) red[j >> 6] = t1;
  __syncthreads();
  float s1 = (red[0] + red[1] + red[2] + red[3]) * (1.f/256.f);
  __syncthreads();
  float t2 = wave_reduce_sum(gx * xhj);
  if ((j & 63) == 0) red[j >> 6] = t2;
  __syncthreads();
  float s2m = (red[0] + red[1] + red[2] + red[3]) * (1.f/256.f);
  float nid = rstd * (gx - s1 - xhj * s2m);
  dout[OFF_NEWINST + b*256 + j] = nid;
}

// ---------------------------------------------------------------------------
extern "C" void kernel_launch(void* const* d_in, const int* in_sizes, int n_in,
                              void* d_out, int out_size, void* d_ws, size_t ws_size,
                              hipStream_t stream) {
  const float* x          = (const float*)d_in[0];
  const float* y          = (const float*)d_in[1];
  const float* m          = (const float*)d_in[2];
  const float* h          = (const float*)d_in[3];
  const float* delta      = (const float*)d_in[4];
  const float* inst_delta = (const float*)d_in[5];
  const float* prod_jac   = (const float*)d_in[6];
  const float* t          = (const float*)d_in[8];
  const float* Wiz  = (const float*)d_in[9];
  const float* biz  = (const float*)d_in[10];
  const float* Whz  = (const float*)d_in[11];
  const float* Wir  = (const float*)d_in[12];
  const float* bir  = (const float*)d_in[13];
  const float* Whr  = (const float*)d_in[14];
  const float* Win  = (const float*)d_in[15];
  const float* bin_ = (const float*)d_in[16];
  const float* Whn  = (const float*)d_in[17];
  const float* bhn  = (const float*)d_in[18];
  const float* ln_scale = (const float*)d_in[19];
  const float* ln_bias  = (const float*)d_in[20];
  const float* Wout = (const float*)d_in[21];
  const float* bout = (const float*)d_in[22];

  float* dout = (float*)d_out;
  float* ws = (float*)d_ws;

  gates_kernel<<<1024, 256, 0, stream>>>(x, h, t, Wiz, biz, Whz, Wir, bir, Whr,
                                         Win, bin_, Whn, bhn, dout, ws);
  solve_kernel<<<1024, 1024, 0, stream>>>(Whz, Whn, Whr, ws, delta, inst_delta, dout);
  pj_gemm_kernel<<<1024, 512, 0, stream>>>(prod_jac, dout + OFF_JAC,
                                           dout + OFF_NEWPJ, dout + OFF_PJNORM);
  readout_kernel<<<1024, 256, 0, stream>>>(y, m, ln_scale, ln_bias, Wout, bout, dout);
}

// Round 2
// 2757.305 us; speedup vs baseline: 1.1599x; 1.1599x over previous
//
#include <hip/hip_runtime.h>
#include <hip/hip_bf16.h>

#define B_N 1024
#define H_N 256
#define O_N 128
#define D_N 64

// d_out offsets (f32 elements), reference tuple order
#define OFF_NEWH      0
#define OFF_NEWDELTA  262144
#define OFF_NEWINST   524288
#define OFF_NEWPJ     786432
#define OFF_NEWMEAN   67895296
#define OFF_NEWT      68157440
#define OFF_OUT       68158464
#define OFF_HCOPY     68289536
#define OFF_DELTAOUT  68551680
#define OFF_HNORM     68682752
#define OFF_DNORM     68683776
#define OFF_PJNORM    68684800
#define OFF_JAC       68685824

typedef __attribute__((ext_vector_type(8))) short short8;
typedef __attribute__((ext_vector_type(4))) float f32x4;

__device__ __forceinline__ short f2bf(float f){
  union { float f; unsigned u; } v; v.f = f;
  unsigned r = v.u + 0x7fffu + ((v.u >> 16) & 1u);
  return (short)(r >> 16);
}

__device__ __forceinline__ float wave_reduce_sum(float v){
  #pragma unroll
  for (int off = 32; off > 0; off >>= 1) v += __shfl_xor(v, off);
  return v;
}

// ---------------------------------------------------------------------------
// Kernel 1: GRU gates, new_h, a-vectors, h copy, new_t, h_norm
// ---------------------------------------------------------------------------
__global__ __launch_bounds__(256) void gates_kernel(
    const float* __restrict__ x, const float* __restrict__ h, const float* __restrict__ tt,
    const float* __restrict__ Wiz, const float* __restrict__ biz, const float* __restrict__ Whz,
    const float* __restrict__ Wir, const float* __restrict__ bir, const float* __restrict__ Whr,
    const float* __restrict__ Win, const float* __restrict__ bin_, const float* __restrict__ Whn,
    const float* __restrict__ bhn,
    float* __restrict__ dout, float* __restrict__ ws)
{
  int b = blockIdx.x, j = threadIdx.x;
  __shared__ float xs[64];
  __shared__ float hs[256];
  __shared__ float red[4];
  if (j < 64) xs[j] = x[b*64 + j];
  float hj = h[b*256 + j];
  hs[j] = hj;
  __syncthreads();

  float zp = biz[j], rp = bir[j], np = bin_[j], g = bhn[j];
  #pragma unroll 8
  for (int k = 0; k < 64; k++){
    float xv = xs[k];
    zp = fmaf(xv, Wiz[k*256 + j], zp);
    rp = fmaf(xv, Wir[k*256 + j], rp);
    np = fmaf(xv, Win[k*256 + j], np);
  }
  #pragma unroll 8
  for (int k = 0; k < 256; k++){
    float hv = hs[k];
    zp = fmaf(hv, Whz[k*256 + j], zp);
    rp = fmaf(hv, Whr[k*256 + j], rp);
    g  = fmaf(hv, Whn[k*256 + j], g);
  }
  float r = 1.f / (1.f + expf(-rp));
  float z = 1.f / (1.f + expf(-zp));
  float n = tanhf(np + r*g);
  float nh = (1.f - z)*n + z*hj;

  float dz = z*(1.f - z);
  float dn = 1.f - n*n;
  float drv = r*(1.f - r);
  float az = (hj - n)*dz;
  float an = (1.f - z)*dn*r;
  float ar = (1.f - z)*dn*g*drv;

  dout[OFF_NEWH   + b*256 + j] = nh;
  dout[OFF_NEWMEAN+ b*256 + j] = nh;
  dout[OFF_HCOPY  + b*256 + j] = hj;
  ws[0*262144 + b*256 + j] = z;
  ws[1*262144 + b*256 + j] = az;
  ws[2*262144 + b*256 + j] = an;
  ws[3*262144 + b*256 + j] = ar;

  float s = wave_reduce_sum(nh*nh);
  if ((j & 63) == 0) red[j >> 6] = s;
  __syncthreads();
  if (j == 0){
    dout[OFF_HNORM + b] = sqrtf(red[0] + red[1] + red[2] + red[3]);
    dout[OFF_NEWT + b] = tt[b] + 1.f;
  }
}

// ---------------------------------------------------------------------------
// Kernel 2: build jac + register-tiled Gauss-Jordan solve with partial
// pivoting.  One block per batch; 16 waves; wave = 64x64 tile (wr,wc),
// lane = 8x8 tile (lr,lc).  A[8][8] in registers, all indices static.
// 2 barriers/iter; pivot selected redundantly in every wave; used-mask in
// registers (uniform).
// ---------------------------------------------------------------------------
__global__ __launch_bounds__(1024) void solve_kernel(
    const float* __restrict__ Whz, const float* __restrict__ Whn, const float* __restrict__ Whr,
    const float* __restrict__ ws, const float* __restrict__ delta,
    const float* __restrict__ inst_delta, float* __restrict__ dout)
{
  const int b = blockIdx.x, tid = threadIdx.x;
  const int l  = tid & 63;
  const int w  = tid >> 6;
  const int wr = w >> 2, wc = w & 3;
  const int lr = l >> 3, lc = l & 7;
  const int r0 = wr*64 + lr*8;   // first row of this lane's tile
  const int c0 = wc*64 + lc*8;   // first col

  __shared__ float colbuf[2][256];
  __shared__ float rowbuf[256];
  __shared__ float rhs[256];
  __shared__ float pivval[256];
  __shared__ int   perm[256];

  // ---- build A tile (and write jac to d_out) ----
  float az[8], an[8], ar[8], zc[8];
  {
    const float4* pz = (const float4*)(ws + 0*262144 + b*256 + c0);
    const float4* pa = (const float4*)(ws + 1*262144 + b*256 + c0);
    const float4* pn = (const float4*)(ws + 2*262144 + b*256 + c0);
    const float4* pr = (const float4*)(ws + 3*262144 + b*256 + c0);
    #pragma unroll
    for (int q = 0; q < 2; q++){
      float4 vz = pz[q], va = pa[q], vn = pn[q], vr = pr[q];
      zc[q*4+0]=vz.x; zc[q*4+1]=vz.y; zc[q*4+2]=vz.z; zc[q*4+3]=vz.w;
      az[q*4+0]=va.x; az[q*4+1]=va.y; az[q*4+2]=va.z; az[q*4+3]=va.w;
      an[q*4+0]=vn.x; an[q*4+1]=vn.y; an[q*4+2]=vn.z; an[q*4+3]=vn.w;
      ar[q*4+0]=vr.x; ar[q*4+1]=vr.y; ar[q*4+2]=vr.z; ar[q*4+3]=vr.w;
    }
  }

  float A[8][8];
  float* jac_out = dout + OFF_JAC + (size_t)b*65536;
  #pragma unroll
  for (int i = 0; i < 8; i++){
    const int row = r0 + i;
    const float4* wz = (const float4*)(Whz + row*256 + c0);
    const float4* wn = (const float4*)(Whn + row*256 + c0);
    const float4* wq = (const float4*)(Whr + row*256 + c0);
    #pragma unroll
    for (int q = 0; q < 2; q++){
      float4 vz = wz[q], vn = wn[q], vr = wq[q];
      A[i][q*4+0] = fmaf(vz.x, az[q*4+0], fmaf(vn.x, an[q*4+0], vr.x*ar[q*4+0]));
      A[i][q*4+1] = fmaf(vz.y, az[q*4+1], fmaf(vn.y, an[q*4+1], vr.y*ar[q*4+1]));
      A[i][q*4+2] = fmaf(vz.z, az[q*4+2], fmaf(vn.z, an[q*4+2], vr.z*ar[q*4+2]));
      A[i][q*4+3] = fmaf(vz.w, az[q*4+3], fmaf(vn.w, an[q*4+3], vr.w*ar[q*4+3]));
    }
    #pragma unroll
    for (int j = 0; j < 8; j++)
      if (c0 + j == row) A[i][j] += zc[j];
    float4 s0 = make_float4(A[i][0], A[i][1], A[i][2], A[i][3]);
    float4 s1 = make_float4(A[i][4], A[i][5], A[i][6], A[i][7]);
    *(float4*)(jac_out + row*256 + c0)     = s0;
    *(float4*)(jac_out + row*256 + c0 + 4) = s1;
  }

  if (tid < 256) rhs[tid] = delta[b*256 + tid] - inst_delta[b*256 + tid];
  // stash column 0
  if (wc == 0 && lc == 0){
    *(float4*)&colbuf[0][r0]     = make_float4(A[0][0], A[1][0], A[2][0], A[3][0]);
    *(float4*)&colbuf[0][r0 + 4] = make_float4(A[4][0], A[5][0], A[6][0], A[7][0]);
  }
  unsigned long long used[4] = {0ull, 0ull, 0ull, 0ull};
  __syncthreads();

  for (int k = 0; k < 256; k++){
    const int kb = k & 1;
    // ---- phase 1: pivot scan (redundant in every wave) ----
    float best = -1.f, bval = 0.f; int bidx = 0;
    #pragma unroll
    for (int q = 0; q < 4; q++){
      int rr = l + q*64;
      float v = colbuf[kb][rr];
      bool fresh = ((used[q] >> l) & 1ull) == 0ull;
      float sc = fresh ? fabsf(v) : -1.f;
      bool better = sc > best;
      best = better ? sc : best;
      bidx = better ? rr : bidx;
      bval = better ? v : bval;
    }
    #pragma unroll
    for (int off = 32; off > 0; off >>= 1){
      float ob = __shfl_xor(best, off);
      int   oi = __shfl_xor(bidx, off);
      float ov = __shfl_xor(bval, off);
      bool take = (ob > best) || (ob == best && oi < bidx);
      best = take ? ob : best;
      bidx = take ? oi : bidx;
      bval = take ? ov : bval;
    }
    const int p = bidx;
    const float ipv = 1.0f / bval;
    {
      const int pq = p >> 6;
      const unsigned long long bit = 1ull << (p & 63);
      #pragma unroll
      for (int q = 0; q < 4; q++) used[q] |= (pq == q) ? bit : 0ull;
    }

    // ---- phase 2a: extract pivot row -> rowbuf (4 waves, 8-select) ----
    if (wr == (p >> 6)){
      const int plr = (p >> 3) & 7, pii = p & 7;
      float rv[8];
      #pragma unroll
      for (int j = 0; j < 8; j++){
        float s = A[0][j];
        #pragma unroll
        for (int ii = 1; ii < 8; ii++) s = (pii == ii) ? A[ii][j] : s;
        rv[j] = s;
      }
      if (lr == plr){
        *(float4*)&rowbuf[c0]     = make_float4(rv[0], rv[1], rv[2], rv[3]);
        *(float4*)&rowbuf[c0 + 4] = make_float4(rv[4], rv[5], rv[6], rv[7]);
      }
    }
    // ---- phase 2b: rhs update ----
    if (tid < 256 && tid != p){
      rhs[tid] -= colbuf[kb][tid] * ipv * rhs[p];
    }
    __syncthreads();

    // ---- phase 3: rank-1 update + stash col k+1 ----
    {
      float m0[8];
      float4 ma = *(const float4*)&colbuf[kb][r0];
      float4 mb = *(const float4*)&colbuf[kb][r0 + 4];
      m0[0]=ma.x; m0[1]=ma.y; m0[2]=ma.z; m0[3]=ma.w;
      m0[4]=mb.x; m0[5]=mb.y; m0[6]=mb.z; m0[7]=mb.w;
      if (wr == (p >> 6)){
        const int plr = (p >> 3) & 7, pii = p & 7;
        const bool act = (lr == plr);
        #pragma unroll
        for (int ii = 0; ii < 8; ii++) m0[ii] = (act && ii == pii) ? 0.f : m0[ii];
      }
      float4 ra = *(const float4*)&rowbuf[c0];
      float4 rb = *(const float4*)&rowbuf[c0 + 4];
      float sf[8];
      sf[0]=ra.x*ipv; sf[1]=ra.y*ipv; sf[2]=ra.z*ipv; sf[3]=ra.w*ipv;
      sf[4]=rb.x*ipv; sf[5]=rb.y*ipv; sf[6]=rb.z*ipv; sf[7]=rb.w*ipv;
      #pragma unroll
      for (int i = 0; i < 8; i++)
        #pragma unroll
        for (int j = 0; j < 8; j++)
          A[i][j] = fmaf(-m0[i], sf[j], A[i][j]);

      if (k < 255){
        const int c = k + 1;
        if (wc == (c >> 6)){
          const int plc = (c >> 3) & 7, pjj = c & 7;
          float cv[8];
          #pragma unroll
          for (int i = 0; i < 8; i++){
            float s = A[i][0];
            #pragma unroll
            for (int jj = 1; jj < 8; jj++) s = (pjj == jj) ? A[i][jj] : s;
            cv[i] = s;
          }
          if (lc == plc){
            *(float4*)&colbuf[kb ^ 1][r0]     = make_float4(cv[0], cv[1], cv[2], cv[3]);
            *(float4*)&colbuf[kb ^ 1][r0 + 4] = make_float4(cv[4], cv[5], cv[6], cv[7]);
          }
        }
      }
      if (tid == 0){ perm[k] = p; pivval[k] = bval; }
    }
    __syncthreads();
  }

  if (tid < 256){
    float xv = rhs[perm[tid]] / pivval[tid];
    dout[OFF_NEWDELTA + b*256 + tid] = xv;
    rowbuf[tid] = xv*xv;
  }
  __syncthreads();
  if (tid < 64){
    float s = rowbuf[tid] + rowbuf[tid+64] + rowbuf[tid+128] + rowbuf[tid+192];
    s = wave_reduce_sum(s);
    if (tid == 0) dout[OFF_DNORM + b] = sqrtf(s);
  }
}

// ---------------------------------------------------------------------------
// Kernel 3: new_prod_jac[b] = prod_jac[b] @ jac[b]  (bf16 MFMA, f32 LDS pad-33)
// one block (512 thr, 8 waves as 2x4) per batch; + Frobenius norm epilogue
// ---------------------------------------------------------------------------
__global__ __launch_bounds__(512) void pj_gemm_kernel(
    const float* __restrict__ prod_jac, const float* __restrict__ jac,
    float* __restrict__ out_pj, float* __restrict__ out_norm)
{
  int b = blockIdx.x, tid = threadIdx.x;
  int l = tid & 63, wid = tid >> 6;
  int wm = wid >> 2, wn = wid & 3;
  int lr = l & 15, lg = l >> 4;

  __shared__ float As[256*33];
  __shared__ float Bs[256*33];

  const float* Ag = prod_jac + (size_t)b*65536;
  const float* Bg = jac      + (size_t)b*65536;

  f32x4 acc[8][4];
  #pragma unroll
  for (int i = 0; i < 8; i++)
    #pragma unroll
    for (int jn = 0; jn < 4; jn++) acc[i][jn] = (f32x4){0.f,0.f,0.f,0.f};

  const int arow = tid >> 1, acolb = (tid & 1)*16;
  const int bk = tid >> 4, bcolb = (tid & 15)*16;

  for (int kt = 0; kt < 8; ++kt){
    const int k0 = kt*32;
    __syncthreads();
    {
      const float4* asrc = (const float4*)(Ag + arow*256 + k0 + acolb);
      float* ad = &As[arow*33 + acolb];
      #pragma unroll
      for (int q = 0; q < 4; q++){
        float4 v = asrc[q];
        ad[q*4+0]=v.x; ad[q*4+1]=v.y; ad[q*4+2]=v.z; ad[q*4+3]=v.w;
      }
      const float4* bsrc = (const float4*)(Bg + (k0 + bk)*256 + bcolb);
      #pragma unroll
      for (int q = 0; q < 4; q++){
        float4 v = bsrc[q];
        Bs[(bcolb+q*4+0)*33 + bk] = v.x;
        Bs[(bcolb+q*4+1)*33 + bk] = v.y;
        Bs[(bcolb+q*4+2)*33 + bk] = v.z;
        Bs[(bcolb+q*4+3)*33 + bk] = v.w;
      }
    }
    __syncthreads();

    short8 bfr[4];
    #pragma unroll
    for (int ni = 0; ni < 4; ni++){
      const float* bp = &Bs[(wn*64 + ni*16 + lr)*33 + lg*8];
      short8 t;
      #pragma unroll
      for (int v = 0; v < 8; v++) t[v] = f2bf(bp[v]);
      bfr[ni] = t;
    }
    #pragma unroll
    for (int mi = 0; mi < 8; mi++){
      const float* ap = &As[(wm*128 + mi*16 + lr)*33 + lg*8];
      short8 af;
      #pragma unroll
      for (int v = 0; v < 8; v++) af[v] = f2bf(ap[v]);
      #pragma unroll
      for (int ni = 0; ni < 4; ni++)
        acc[mi][ni] = __builtin_amdgcn_mfma_f32_16x16x32_bf16(af, bfr[ni], acc[mi][ni], 0, 0, 0);
    }
  }

  float nrm = 0.f;
  #pragma unroll
  for (int mi = 0; mi < 8; mi++){
    #pragma unroll
    for (int ni = 0; ni < 4; ni++){
      #pragma unroll
      for (int rr = 0; rr < 4; rr++){
        int row = wm*128 + mi*16 + lg*4 + rr;
        int col = wn*64 + ni*16 + lr;
        float vv = acc[mi][ni][rr];
        out_pj[(size_t)b*65536 + row*256 + col] = vv;
        nrm += vv*vv;
      }
    }
  }
  __syncthreads();
  As[tid] = nrm;
  __syncthreads();
  if (tid < 64){
    float s = 0.f;
    #pragma unroll
    for (int q = 0; q < 8; q++) s += As[tid + q*64];
    s = wave_reduce_sum(s);
    if (tid == 0) out_norm[b] = sqrtf(s);
  }
}

// ---------------------------------------------------------------------------
// Kernel 4: readout (LayerNorm + Wout), out, delta_output, LN-VJP inst_delta
// ---------------------------------------------------------------------------
__global__ __launch_bounds__(256) void readout_kernel(
    const float* __restrict__ y, const float* __restrict__ m,
    const float* __restrict__ ln_scale, const float* __restrict__ ln_bias,
    const float* __restrict__ Wout, const float* __restrict__ bout,
    float* __restrict__ dout)
{
  int b = blockIdx.x, j = threadIdx.x;
  __shared__ float lno[256], xh[256], go[128], red2[256], red[4];

  float hv = dout[OFF_NEWH + b*256 + j];
  float s = wave_reduce_sum(hv);
  if ((j & 63) == 0) red[j >> 6] = s;
  __syncthreads();
  float mu = (red[0] + red[1] + red[2] + red[3]) * (1.f/256.f);
  __syncthreads();
  float d = hv - mu;
  float sv = wave_reduce_sum(d*d);
  if ((j & 63) == 0) red[j >> 6] = sv;
  __syncthreads();
  float var = (red[0] + red[1] + red[2] + red[3]) * (1.f/256.f);
  float rstd = rsqrtf(var + 1e-6f);
  float xhj = d * rstd;
  xh[j] = xhj;
  lno[j] = xhj * ln_scale[j] + ln_bias[j];
  __syncthreads();

  // forward o = lno @ Wout + bout, split across thread halves
  int i = j & 127, half = j >> 7;
  float part = half ? 0.f : bout[i];
  #pragma unroll 8
  for (int jj = half*128; jj < half*128 + 128; jj++)
    part = fmaf(lno[jj], Wout[jj*128 + i], part);
  red2[j] = part;
  __syncthreads();
  if (j < 128){
    float o = red2[j] + red2[j + 128];
    float gv = 2.f * m[b*128 + j] * (o - y[b*128 + j]);
    dout[OFF_OUT + b*128 + j] = o;
    dout[OFF_DELTAOUT + b*128 + j] = gv;
    go[j] = gv;
  }
  __syncthreads();

  // backward through Wout and LayerNorm
  float gl = 0.f;
  const float4* wrow = (const float4*)(Wout + j*128);
  #pragma unroll 8
  for (int q = 0; q < 32; q++){
    float4 w = wrow[q];
    gl = fmaf(w.x, go[q*4+0], gl);
    gl = fmaf(w.y, go[q*4+1], gl);
    gl = fmaf(w.z, go[q*4+2], gl);
    gl = fmaf(w.w, go[q*4+3], gl);
  }
  float gx = gl * ln_scale[j];
  __syncthreads();
  float t1 = wave_reduce_sum(gx);
  if ((j & 63) == 0) red[j >> 6] = t1;
  __syncthreads();
  float s1 = (red[0] + red[1] + red[2] + red[3]) * (1.f/256.f);
  __syncthreads();
  float t2 = wave_reduce_sum(gx * xhj);
  if ((j & 63) == 0) red[j >> 6] = t2;
  __syncthreads();
  float s2m = (red[0] + red[1] + red[2] + red[3]) * (1.f/256.f);
  float nid = rstd * (gx - s1 - xhj * s2m);
  dout[OFF_NEWINST + b*256 + j] = nid;
}

// ---------------------------------------------------------------------------
extern "C" void kernel_launch(void* const* d_in, const int* in_sizes, int n_in,
                              void* d_out, int out_size, void* d_ws, size_t ws_size,
                              hipStream_t stream) {
  const float* x          = (const float*)d_in[0];
  const float* y          = (const float*)d_in[1];
  const float* m          = (const float*)d_in[2];
  const float* h          = (const float*)d_in[3];
  const float* delta      = (const float*)d_in[4];
  const float* inst_delta = (const float*)d_in[5];
  const float* prod_jac   = (const float*)d_in[6];
  const float* t          = (const float*)d_in[8];
  const float* Wiz  = (const float*)d_in[9];
  const float* biz  = (const float*)d_in[10];
  const float* Whz  = (const float*)d_in[11];
  const float* Wir  = (const float*)d_in[12];
  const float* bir  = (const float*)d_in[13];
  const float* Whr  = (const float*)d_in[14];
  const float* Win  = (const float*)d_in[15];
  const float* bin_ = (const float*)d_in[16];
  const float* Whn  = (const float*)d_in[17];
  const float* bhn  = (const float*)d_in[18];
  const float* ln_scale = (const float*)d_in[19];
  const float* ln_bias  = (const float*)d_in[20];
  const float* Wout = (const float*)d_in[21];
  const float* bout = (const float*)d_in[22];

  float* dout = (float*)d_out;
  float* ws = (float*)d_ws;

  gates_kernel<<<1024, 256, 0, stream>>>(x, h, t, Wiz, biz, Whz, Wir, bir, Whr,
                                         Win, bin_, Whn, bhn, dout, ws);
  solve_kernel<<<1024, 1024, 0, stream>>>(Whz, Whn, Whr, ws, delta, inst_delta, dout);
  pj_gemm_kernel<<<1024, 512, 0, stream>>>(prod_jac, dout + OFF_JAC,
                                           dout + OFF_NEWPJ, dout + OFF_PJNORM);
  readout_kernel<<<1024, 256, 0, stream>>>(y, m, ln_scale, ln_bias, Wout, bout, dout);
}

// Round 3
// 2634.248 us; speedup vs baseline: 1.2141x; 1.0467x over previous
//
#include <hip/hip_runtime.h>
#include <hip/hip_bf16.h>

#define B_N 1024
#define H_N 256
#define O_N 128
#define D_N 64

// d_out offsets (f32 elements), reference tuple order
#define OFF_NEWH      0
#define OFF_NEWDELTA  262144
#define OFF_NEWINST   524288
#define OFF_NEWPJ     786432
#define OFF_NEWMEAN   67895296
#define OFF_NEWT      68157440
#define OFF_OUT       68158464
#define OFF_HCOPY     68289536
#define OFF_DELTAOUT  68551680
#define OFF_HNORM     68682752
#define OFF_DNORM     68683776
#define OFF_PJNORM    68684800
#define OFF_JAC       68685824

typedef __attribute__((ext_vector_type(8))) short short8;
typedef __attribute__((ext_vector_type(4))) float f32x4;

__device__ __forceinline__ short f2bf(float f){
  union { float f; unsigned u; } v; v.f = f;
  unsigned r = v.u + 0x7fffu + ((v.u >> 16) & 1u);
  return (short)(r >> 16);
}

__device__ __forceinline__ float wave_reduce_sum(float v){
  #pragma unroll
  for (int off = 32; off > 0; off >>= 1) v += __shfl_xor(v, off);
  return v;
}

// ---------------------------------------------------------------------------
// Kernel 1: GRU gates, new_h, a-vectors, h copy, new_t, h_norm
// ---------------------------------------------------------------------------
__global__ __launch_bounds__(256) void gates_kernel(
    const float* __restrict__ x, const float* __restrict__ h, const float* __restrict__ tt,
    const float* __restrict__ Wiz, const float* __restrict__ biz, const float* __restrict__ Whz,
    const float* __restrict__ Wir, const float* __restrict__ bir, const float* __restrict__ Whr,
    const float* __restrict__ Win, const float* __restrict__ bin_, const float* __restrict__ Whn,
    const float* __restrict__ bhn,
    float* __restrict__ dout, float* __restrict__ ws)
{
  int b = blockIdx.x, j = threadIdx.x;
  __shared__ float xs[64];
  __shared__ float hs[256];
  __shared__ float red[4];
  if (j < 64) xs[j] = x[b*64 + j];
  float hj = h[b*256 + j];
  hs[j] = hj;
  __syncthreads();

  float zp = biz[j], rp = bir[j], np = bin_[j], g = bhn[j];
  #pragma unroll 8
  for (int k = 0; k < 64; k++){
    float xv = xs[k];
    zp = fmaf(xv, Wiz[k*256 + j], zp);
    rp = fmaf(xv, Wir[k*256 + j], rp);
    np = fmaf(xv, Win[k*256 + j], np);
  }
  #pragma unroll 8
  for (int k = 0; k < 256; k++){
    float hv = hs[k];
    zp = fmaf(hv, Whz[k*256 + j], zp);
    rp = fmaf(hv, Whr[k*256 + j], rp);
    g  = fmaf(hv, Whn[k*256 + j], g);
  }
  float r = 1.f / (1.f + expf(-rp));
  float z = 1.f / (1.f + expf(-zp));
  float n = tanhf(np + r*g);
  float nh = (1.f - z)*n + z*hj;

  float dz = z*(1.f - z);
  float dn = 1.f - n*n;
  float drv = r*(1.f - r);
  float az = (hj - n)*dz;
  float an = (1.f - z)*dn*r;
  float ar = (1.f - z)*dn*g*drv;

  dout[OFF_NEWH   + b*256 + j] = nh;
  dout[OFF_NEWMEAN+ b*256 + j] = nh;
  dout[OFF_HCOPY  + b*256 + j] = hj;
  ws[0*262144 + b*256 + j] = z;
  ws[1*262144 + b*256 + j] = az;
  ws[2*262144 + b*256 + j] = an;
  ws[3*262144 + b*256 + j] = ar;

  float s = wave_reduce_sum(nh*nh);
  if ((j & 63) == 0) red[j >> 6] = s;
  __syncthreads();
  if (j == 0){
    dout[OFF_HNORM + b] = sqrtf(red[0] + red[1] + red[2] + red[3]);
    dout[OFF_NEWT + b] = tt[b] + 1.f;
  }
}

// ---------------------------------------------------------------------------
// Kernel 2: build jac + register-tiled Gauss-Jordan solve with partial
// pivoting.  One block per batch; 16 waves; wave = 64x64 tile (wr,wc),
// lane = 8x8 tile (lr,lc).  A[8][8] in registers, all indices static.
// __launch_bounds__(1024,4): 4 waves/EU -> 128 ARCH VGPRs, no AGPR split
// (r2's 64V+64A split tripled the inner-loop VALU ops via accvgpr round
// trips; occupancy is 1 block/CU either way).
// ---------------------------------------------------------------------------
__global__ __launch_bounds__(1024, 4) void solve_kernel(
    const float* __restrict__ Whz, const float* __restrict__ Whn, const float* __restrict__ Whr,
    const float* __restrict__ ws, const float* __restrict__ delta,
    const float* __restrict__ inst_delta, float* __restrict__ dout)
{
  const int b = blockIdx.x, tid = threadIdx.x;
  const int l  = tid & 63;
  const int w  = tid >> 6;
  const int wr = w >> 2, wc = w & 3;
  const int lr = l >> 3, lc = l & 7;
  const int r0 = wr*64 + lr*8;   // first row of this lane's tile
  const int c0 = wc*64 + lc*8;   // first col

  __shared__ __align__(16) float colbuf[2][256];
  __shared__ __align__(16) float rowbuf[256];
  __shared__ __align__(16) float rhs[256];
  __shared__ __align__(16) float pivval[256];
  __shared__ int   perm[256];

  // ---- build A tile (and write jac to d_out) ----
  float az[8], an[8], ar[8], zc[8];
  {
    const float4* pz = (const float4*)(ws + 0*262144 + b*256 + c0);
    const float4* pa = (const float4*)(ws + 1*262144 + b*256 + c0);
    const float4* pn = (const float4*)(ws + 2*262144 + b*256 + c0);
    const float4* pr = (const float4*)(ws + 3*262144 + b*256 + c0);
    #pragma unroll
    for (int q = 0; q < 2; q++){
      float4 vz = pz[q], va = pa[q], vn = pn[q], vr = pr[q];
      zc[q*4+0]=vz.x; zc[q*4+1]=vz.y; zc[q*4+2]=vz.z; zc[q*4+3]=vz.w;
      az[q*4+0]=va.x; az[q*4+1]=va.y; az[q*4+2]=va.z; az[q*4+3]=va.w;
      an[q*4+0]=vn.x; an[q*4+1]=vn.y; an[q*4+2]=vn.z; an[q*4+3]=vn.w;
      ar[q*4+0]=vr.x; ar[q*4+1]=vr.y; ar[q*4+2]=vr.z; ar[q*4+3]=vr.w;
    }
  }

  float A[8][8];
  float* jac_out = dout + OFF_JAC + (size_t)b*65536;
  #pragma unroll
  for (int i = 0; i < 8; i++){
    const int row = r0 + i;
    const float4* wz = (const float4*)(Whz + row*256 + c0);
    const float4* wn = (const float4*)(Whn + row*256 + c0);
    const float4* wq = (const float4*)(Whr + row*256 + c0);
    #pragma unroll
    for (int q = 0; q < 2; q++){
      float4 vz = wz[q], vn = wn[q], vr = wq[q];
      A[i][q*4+0] = fmaf(vz.x, az[q*4+0], fmaf(vn.x, an[q*4+0], vr.x*ar[q*4+0]));
      A[i][q*4+1] = fmaf(vz.y, az[q*4+1], fmaf(vn.y, an[q*4+1], vr.y*ar[q*4+1]));
      A[i][q*4+2] = fmaf(vz.z, az[q*4+2], fmaf(vn.z, an[q*4+2], vr.z*ar[q*4+2]));
      A[i][q*4+3] = fmaf(vz.w, az[q*4+3], fmaf(vn.w, an[q*4+3], vr.w*ar[q*4+3]));
    }
    #pragma unroll
    for (int j = 0; j < 8; j++)
      if (c0 + j == row) A[i][j] += zc[j];
    float4 s0 = make_float4(A[i][0], A[i][1], A[i][2], A[i][3]);
    float4 s1 = make_float4(A[i][4], A[i][5], A[i][6], A[i][7]);
    *(float4*)(jac_out + row*256 + c0)     = s0;
    *(float4*)(jac_out + row*256 + c0 + 4) = s1;
  }

  if (tid < 256) rhs[tid] = delta[b*256 + tid] - inst_delta[b*256 + tid];
  // stash column 0
  if (wc == 0 && lc == 0){
    *(float4*)&colbuf[0][r0]     = make_float4(A[0][0], A[1][0], A[2][0], A[3][0]);
    *(float4*)&colbuf[0][r0 + 4] = make_float4(A[4][0], A[5][0], A[6][0], A[7][0]);
  }
  unsigned usedbits = 0u;   // 4 bits: rows 4l..4l+3 already pivoted
  __syncthreads();

  for (int k = 0; k < 256; k++){
    const int kb = k & 1;
    // ---- phase 1: pivot scan (redundant in every wave, 1 ds_read_b128) ----
    float4 cv4 = *(const float4*)&colbuf[kb][l*4];
    float best = -1.f, bval = 0.f; int bidx = 0;
    {
      float c4[4] = {cv4.x, cv4.y, cv4.z, cv4.w};
      #pragma unroll
      for (int q = 0; q < 4; q++){
        float v = c4[q];
        float sc = ((usedbits >> q) & 1u) ? -1.f : fabsf(v);
        bool better = sc > best;
        best = better ? sc : best;
        bidx = better ? (l*4 + q) : bidx;
        bval = better ? v : bval;
      }
    }
    #pragma unroll
    for (int off = 32; off > 0; off >>= 1){
      float ob = __shfl_xor(best, off);
      int   oi = __shfl_xor(bidx, off);
      float ov = __shfl_xor(bval, off);
      bool take = (ob > best) || (ob == best && oi < bidx);
      best = take ? ob : best;
      bidx = take ? oi : bidx;
      bval = take ? ov : bval;
    }
    const int p = bidx;
    const float ipv = 1.0f / bval;
    usedbits |= ((p >> 2) == l) ? (1u << (p & 3)) : 0u;

    // ---- phase 2a: extract pivot row -> rowbuf (4 waves, 8-select) ----
    if (wr == (p >> 6)){
      const int plr = (p >> 3) & 7, pii = p & 7;
      float rv[8];
      #pragma unroll
      for (int j = 0; j < 8; j++){
        float s = A[0][j];
        #pragma unroll
        for (int ii = 1; ii < 8; ii++) s = (pii == ii) ? A[ii][j] : s;
        rv[j] = s;
      }
      if (lr == plr){
        *(float4*)&rowbuf[c0]     = make_float4(rv[0], rv[1], rv[2], rv[3]);
        *(float4*)&rowbuf[c0 + 4] = make_float4(rv[4], rv[5], rv[6], rv[7]);
      }
    }
    // ---- phase 2b: rhs update ----
    if (tid < 256 && tid != p){
      rhs[tid] -= colbuf[kb][tid] * ipv * rhs[p];
    }
    __syncthreads();

    // ---- phase 3: rank-1 update + stash col k+1 ----
    {
      float m0[8];
      float4 ma = *(const float4*)&colbuf[kb][r0];
      float4 mb = *(const float4*)&colbuf[kb][r0 + 4];
      m0[0]=ma.x; m0[1]=ma.y; m0[2]=ma.z; m0[3]=ma.w;
      m0[4]=mb.x; m0[5]=mb.y; m0[6]=mb.z; m0[7]=mb.w;
      if (wr == (p >> 6)){
        const int plr = (p >> 3) & 7, pii = p & 7;
        const bool act = (lr == plr);
        #pragma unroll
        for (int ii = 0; ii < 8; ii++) m0[ii] = (act && ii == pii) ? 0.f : m0[ii];
      }
      float4 ra = *(const float4*)&rowbuf[c0];
      float4 rb = *(const float4*)&rowbuf[c0 + 4];
      float sf[8];
      sf[0]=ra.x*ipv; sf[1]=ra.y*ipv; sf[2]=ra.z*ipv; sf[3]=ra.w*ipv;
      sf[4]=rb.x*ipv; sf[5]=rb.y*ipv; sf[6]=rb.z*ipv; sf[7]=rb.w*ipv;
      #pragma unroll
      for (int i = 0; i < 8; i++)
        #pragma unroll
        for (int j = 0; j < 8; j++)
          A[i][j] = fmaf(-m0[i], sf[j], A[i][j]);

      if (k < 255){
        const int c = k + 1;
        if (wc == (c >> 6)){
          const int plc = (c >> 3) & 7, pjj = c & 7;
          float cv[8];
          #pragma unroll
          for (int i = 0; i < 8; i++){
            float s = A[i][0];
            #pragma unroll
            for (int jj = 1; jj < 8; jj++) s = (pjj == jj) ? A[i][jj] : s;
            cv[i] = s;
          }
          if (lc == plc){
            *(float4*)&colbuf[kb ^ 1][r0]     = make_float4(cv[0], cv[1], cv[2], cv[3]);
            *(float4*)&colbuf[kb ^ 1][r0 + 4] = make_float4(cv[4], cv[5], cv[6], cv[7]);
          }
        }
      }
      if (tid == 0){ perm[k] = p; pivval[k] = bval; }
    }
    __syncthreads();
  }

  if (tid < 256){
    float xv = rhs[perm[tid]] / pivval[tid];
    dout[OFF_NEWDELTA + b*256 + tid] = xv;
    rowbuf[tid] = xv*xv;
  }
  __syncthreads();
  if (tid < 64){
    float s = rowbuf[tid] + rowbuf[tid+64] + rowbuf[tid+128] + rowbuf[tid+192];
    s = wave_reduce_sum(s);
    if (tid == 0) dout[OFF_DNORM + b] = sqrtf(s);
  }
}

// ---------------------------------------------------------------------------
// Kernel 3: new_prod_jac[b] = prod_jac[b] @ jac[b]  (bf16 MFMA, f32 LDS pad-33)
// one block (512 thr, 8 waves as 2x4) per batch; + Frobenius norm epilogue
// ---------------------------------------------------------------------------
__global__ __launch_bounds__(512) void pj_gemm_kernel(
    const float* __restrict__ prod_jac, const float* __restrict__ jac,
    float* __restrict__ out_pj, float* __restrict__ out_norm)
{
  int b = blockIdx.x, tid = threadIdx.x;
  int l = tid & 63, wid = tid >> 6;
  int wm = wid >> 2, wn = wid & 3;
  int lr = l & 15, lg = l >> 4;

  __shared__ float As[256*33];
  __shared__ float Bs[256*33];

  const float* Ag = prod_jac + (size_t)b*65536;
  const float* Bg = jac      + (size_t)b*65536;

  f32x4 acc[8][4];
  #pragma unroll
  for (int i = 0; i < 8; i++)
    #pragma unroll
    for (int jn = 0; jn < 4; jn++) acc[i][jn] = (f32x4){0.f,0.f,0.f,0.f};

  const int arow = tid >> 1, acolb = (tid & 1)*16;
  const int bk = tid >> 4, bcolb = (tid & 15)*16;

  for (int kt = 0; kt < 8; ++kt){
    const int k0 = kt*32;
    __syncthreads();
    {
      const float4* asrc = (const float4*)(Ag + arow*256 + k0 + acolb);
      float* ad = &As[arow*33 + acolb];
      #pragma unroll
      for (int q = 0; q < 4; q++){
        float4 v = asrc[q];
        ad[q*4+0]=v.x; ad[q*4+1]=v.y; ad[q*4+2]=v.z; ad[q*4+3]=v.w;
      }
      const float4* bsrc = (const float4*)(Bg + (k0 + bk)*256 + bcolb);
      #pragma unroll
      for (int q = 0; q < 4; q++){
        float4 v = bsrc[q];
        Bs[(bcolb+q*4+0)*33 + bk] = v.x;
        Bs[(bcolb+q*4+1)*33 + bk] = v.y;
        Bs[(bcolb+q*4+2)*33 + bk] = v.z;
        Bs[(bcolb+q*4+3)*33 + bk] = v.w;
      }
    }
    __syncthreads();

    short8 bfr[4];
    #pragma unroll
    for (int ni = 0; ni < 4; ni++){
      const float* bp = &Bs[(wn*64 + ni*16 + lr)*33 + lg*8];
      short8 t;
      #pragma unroll
      for (int v = 0; v < 8; v++) t[v] = f2bf(bp[v]);
      bfr[ni] = t;
    }
    #pragma unroll
    for (int mi = 0; mi < 8; mi++){
      const float* ap = &As[(wm*128 + mi*16 + lr)*33 + lg*8];
      short8 af;
      #pragma unroll
      for (int v = 0; v < 8; v++) af[v] = f2bf(ap[v]);
      #pragma unroll
      for (int ni = 0; ni < 4; ni++)
        acc[mi][ni] = __builtin_amdgcn_mfma_f32_16x16x32_bf16(af, bfr[ni], acc[mi][ni], 0, 0, 0);
    }
  }

  float nrm = 0.f;
  #pragma unroll
  for (int mi = 0; mi < 8; mi++){
    #pragma unroll
    for (int ni = 0; ni < 4; ni++){
      #pragma unroll
      for (int rr = 0; rr < 4; rr++){
        int row = wm*128 + mi*16 + lg*4 + rr;
        int col = wn*64 + ni*16 + lr;
        float vv = acc[mi][ni][rr];
        out_pj[(size_t)b*65536 + row*256 + col] = vv;
        nrm += vv*vv;
      }
    }
  }
  __syncthreads();
  As[tid] = nrm;
  __syncthreads();
  if (tid < 64){
    float s = 0.f;
    #pragma unroll
    for (int q = 0; q < 8; q++) s += As[tid + q*64];
    s = wave_reduce_sum(s);
    if (tid == 0) out_norm[b] = sqrtf(s);
  }
}

// ---------------------------------------------------------------------------
// Kernel 4: readout (LayerNorm + Wout), out, delta_output, LN-VJP inst_delta
// ---------------------------------------------------------------------------
__global__ __launch_bounds__(256) void readout_kernel(
    const float* __restrict__ y, const float* __restrict__ m,
    const float* __restrict__ ln_scale, const float* __restrict__ ln_bias,
    const float* __restrict__ Wout, const float* __restrict__ bout,
    float* __restrict__ dout)
{
  int b = blockIdx.x, j = threadIdx.x;
  __shared__ float lno[256], xh[256], go[128], red2[256], red[4];

  float hv = dout[OFF_NEWH + b*256 + j];
  float s = wave_reduce_sum(hv);
  if ((j & 63) == 0) red[j >> 6] = s;
  __syncthreads();
  float mu = (red[0] + red[1] + red[2] + red[3]) * (1.f/256.f);
  __syncthreads();
  float d = hv - mu;
  float sv = wave_reduce_sum(d*d);
  if ((j & 63) == 0) red[j >> 6] = sv;
  __syncthreads();
  float var = (red[0] + red[1] + red[2] + red[3]) * (1.f/256.f);
  float rstd = rsqrtf(var + 1e-6f);
  float xhj = d * rstd;
  xh[j] = xhj;
  lno[j] = xhj * ln_scale[j] + ln_bias[j];
  __syncthreads();

  // forward o = lno @ Wout + bout, split across thread halves
  int i = j & 127, half = j >> 7;
  float part = half ? 0.f : bout[i];
  #pragma unroll 8
  for (int jj = half*128; jj < half*128 + 128; jj++)
    part = fmaf(lno[jj], Wout[jj*128 + i], part);
  red2[j] = part;
  __syncthreads();
  if (j < 128){
    float o = red2[j] + red2[j + 128];
    float gv = 2.f * m[b*128 + j] * (o - y[b*128 + j]);
    dout[OFF_OUT + b*128 + j] = o;
    dout[OFF_DELTAOUT + b*128 + j] = gv;
    go[j] = gv;
  }
  __syncthreads();

  // backward through Wout and LayerNorm
  float gl = 0.f;
  const float4* wrow = (const float4*)(Wout + j*128);
  #pragma unroll 8
  for (int q = 0; q < 32; q++){
    float4 w = wrow[q];
    gl = fmaf(w.x, go[q*4+0], gl);
    gl = fmaf(w.y, go[q*4+1], gl);
    gl = fmaf(w.z, go[q*4+2], gl);
    gl = fmaf(w.w, go[q*4+3], gl);
  }
  float gx = gl * ln_scale[j];
  __syncthreads();
  float t1 = wave_reduce_sum(gx);
  if ((j & 63) == 0) red[j >> 6] = t1;
  __syncthreads();
  float s1 = (red[0] + red[1] + red[2] + red[3]) * (1.f/256.f);
  __syncthreads();
  float t2 = wave_reduce_sum(gx * xhj);
  if ((j & 63) == 0) red[j >> 6] = t2;
  __syncthreads();
  float s2m = (red[0] + red[1] + red[2] + red[3]) * (1.f/256.f);
  float nid = rstd * (gx - s1 - xhj * s2m);
  dout[OFF_NEWINST + b*256 + j] = nid;
}

// ---------------------------------------------------------------------------
extern "C" void kernel_launch(void* const* d_in, const int* in_sizes, int n_in,
                              void* d_out, int out_size, void* d_ws, size_t ws_size,
                              hipStream_t stream) {
  const float* x          = (const float*)d_in[0];
  const float* y          = (const float*)d_in[1];
  const float* m          = (const float*)d_in[2];
  const float* h          = (const float*)d_in[3];
  const float* delta      = (const float*)d_in[4];
  const float* inst_delta = (const float*)d_in[5];
  const float* prod_jac   = (const float*)d_in[6];
  const float* t          = (const float*)d_in[8];
  const float* Wiz  = (const float*)d_in[9];
  const float* biz  = (const float*)d_in[10];
  const float* Whz  = (const float*)d_in[11];
  const float* Wir  = (const float*)d_in[12];
  const float* bir  = (const float*)d_in[13];
  const float* Whr  = (const float*)d_in[14];
  const float* Win  = (const float*)d_in[15];
  const float* bin_ = (const float*)d_in[16];
  const float* Whn  = (const float*)d_in[17];
  const float* bhn  = (const float*)d_in[18];
  const float* ln_scale = (const float*)d_in[19];
  const float* ln_bias  = (const float*)d_in[20];
  const float* Wout = (const float*)d_in[21];
  const float* bout = (const float*)d_in[22];

  float* dout = (float*)d_out;
  float* ws = (float*)d_ws;

  gates_kernel<<<1024, 256, 0, stream>>>(x, h, t, Wiz, biz, Whz, Wir, bir, Whr,
                                         Win, bin_, Whn, bhn, dout, ws);
  solve_kernel<<<1024, 1024, 0, stream>>>(Whz, Whn, Whr, ws, delta, inst_delta, dout);
  pj_gemm_kernel<<<1024, 512, 0, stream>>>(prod_jac, dout + OFF_JAC,
                                           dout + OFF_NEWPJ, dout + OFF_PJNORM);
  readout_kernel<<<1024, 256, 0, stream>>>(y, m, ln_scale, ln_bias, Wout, bout, dout);
}